// Round 9
// baseline (652.567 us; speedup 1.0000x reference)
//
#include <hip/hip_runtime.h>
#include <math.h>

// SSIM loss fp32, B=64 H=W=512, 11x11 Gaussian sigma=1.5, separable (w ⊗ w).
// R17: fixed R14. R14 counters (dur 186us, WRITE_SIZE 58.4MB!, FETCH 288MB,
// VALUBusy 43%) revealed: (a) scratch spills (58MB stores from a kernel that
// writes 16KB), (b) 77 per-step lgkmcnt(0)+sched_barrier(0) full drains
// serialized the march, (c) 22 ds_read_b32/step at ~5.8cy/inst ~= 75us of
// LDS-pipe time. Fixes:
//  - no HW fences: same-wave LDS ops are in-order; a compiler-only barrier
//    (asm "":::"memory") stops read-above-write reordering. Backend emits
//    fine-grained lgkmcnt(N)/vmcnt(N).
//  - 2-deep reg prefetch: step i loads row i+2, writes row i+1 (loaded at
//    i-1) -> 1 step of vmcnt slack x 4 waves/SIMD.
//  - spill control: ring reset folded into dl=10 overwrite-mul; A/B load-reg
//    sets swapped once per 11-step group so ALL indices are compile-time.
//  - window ds_reads batched into arrays (ds_read2 merging); steps 77->74;
//    compile-time EMIT/LD/WR flags; SALU row addressing; XCD-chunked swizzle.
// Geometry unchanged: wave owns 64col x 64row; LDS 5120B; 4096 waves (16/CU).

#define NPART 4096

struct W11 { float w[11]; };

__global__ __launch_bounds__(256, 4) void ssim_main(
    const float* __restrict__ x, const float* __restrict__ y,
    float* __restrict__ partial, W11 wk, int atomic_mode)
{
    // per-wave double-buffered row window: [wave][parity][arr(x,y)][74 pad 80]
    __shared__ float rbuf[4][2][2][80];          // 5120 B

    const int tid = threadIdx.x;
    const int l   = tid & 63;
    const int w   = tid >> 6;
    const int bid = (int)blockIdx.x;
    const int sbid = ((bid & 7) << 7) | (bid >> 3);   // XCD-chunked (1024%8==0)
    const int wid  = sbid * 4 + w;               // 0..4095
    const int seg   = wid & 7;
    const int strip = (wid >> 3) & 7;
    const int z     = wid >> 6;
    const int C0 = strip << 6;
    const int R0 = seg << 6;
    const float* __restrict__ xb = x + (size_t)z * (512 * 512);
    const float* __restrict__ yb = y + (size_t)z * (512 * 512);

    // per-lane column geometry (constant over the march)
    const int   ca  = C0 - 5 + l;
    const float cma = ((unsigned)ca < 512u) ? 1.f : 0.f;
    const int   cac = min(max(ca, 0), 511);
    const bool  tl  = (l >= 54);                 // tail lanes cover slots 64..73
    const int   cb  = C0 + 5 + l;
    const float cmb = ((unsigned)cb < 512u) ? 1.f : 0.f;
    const int   cbc = min(max(cb, 0), 511);

    // v-conv rings; slot s emitted at step i==s (mod 11), restarted via the
    // dl=10 overwrite-mul at step i+1 (overwritten slot is always dead/fresh).
    float ax[11], ay[11], ass[11], axy[11];
    #pragma unroll
    for (int k = 0; k < 11; ++k) { ax[k]=0.f; ay[k]=0.f; ass[k]=0.f; axy[k]=0.f; }
    float lsum = 0.f;

    float Ax, Ay, Axt, Ayt, Bx, By, Bxt, Byt;

    // ---- prologue: A <- row R0-5 -> parity 0 ; B <- row R0-4 (prev for i=0)
    {
        const int hr = R0 - 5;
        Ax = Ay = Axt = Ayt = 0.f;
        if ((unsigned)hr < 512u) {
            const float* __restrict__ rx = xb + hr * 512;
            const float* __restrict__ ry = yb + hr * 512;
            Ax = rx[cac] * cma;  Ay = ry[cac] * cma;
            if (tl) { Axt = rx[cbc] * cmb; Ayt = ry[cbc] * cmb; }
        }
        rbuf[w][0][0][l] = Ax;  rbuf[w][0][1][l] = Ay;
        if (tl) { rbuf[w][0][0][l + 10] = Axt; rbuf[w][0][1][l + 10] = Ayt; }
        const int hr2 = R0 - 4;
        Bx = By = Bxt = Byt = 0.f;
        if ((unsigned)hr2 < 512u) {
            const float* __restrict__ rx = xb + hr2 * 512;
            const float* __restrict__ ry = yb + hr2 * 512;
            Bx = rx[cac] * cma;  By = ry[cac] * cma;
            if (tl) { Bxt = rx[cbc] * cmb; Byt = ry[cbc] * cmb; }
        }
    }
    asm volatile("" ::: "memory");

    // step i (i = 11g+U): LD row R0-3+i -> load-regs; WR prev-regs (row
    // R0-4+i) to parity (i+1)&1; read h-row R0-5+i from parity i&1; ring;
    // emit output row R0-10+i (valid for 10<=i<=73) with weight AW.
#define SSTEP(U, LD, WR, AW, LX, LY, LXT, LYT, PX, PY, PXT, PYT, CXp, CYp, WXp, WYp) \
    {                                                                         \
        if (LD) {                                                             \
            const int hrn = brow + (U);                                       \
            LX = 0.f; LY = 0.f; LXT = 0.f; LYT = 0.f;                         \
            if ((unsigned)hrn < 512u) {                                       \
                const float* __restrict__ rx = xb + hrn * 512;                \
                const float* __restrict__ ry = yb + hrn * 512;                \
                LX = rx[cac] * cma;  LY = ry[cac] * cma;                      \
                if (tl) { LXT = rx[cbc] * cmb; LYT = ry[cbc] * cmb; }         \
            }                                                                 \
        }                                                                     \
        if (WR) {                                                             \
            (WXp)[l] = PX;  (WYp)[l] = PY;                                    \
            if (tl) { (WXp)[l + 10] = PXT; (WYp)[l + 10] = PYT; }             \
        }                                                                     \
        asm volatile("" ::: "memory");                                        \
        float wxv[11], wyv[11];                                               \
        _Pragma("unroll")                                                     \
        for (int dd = 0; dd < 11; ++dd) wxv[dd] = (CXp)[l + dd];              \
        _Pragma("unroll")                                                     \
        for (int dd = 0; dd < 11; ++dd) wyv[dd] = (CYp)[l + dd];              \
        float hx = 0.f, hy = 0.f, hss = 0.f, hxy = 0.f;                       \
        _Pragma("unroll")                                                     \
        for (int dd = 0; dd < 11; ++dd) {                                     \
            const float xs = wxv[dd], ys = wyv[dd], wd = wk.w[dd];            \
            hx  += wd * xs;  hy += wd * ys;                                   \
            hss += wd * (xs * xs + ys * ys);                                  \
            hxy += wd * (xs * ys);                                            \
        }                                                                     \
        _Pragma("unroll")                                                     \
        for (int dl = 0; dl < 10; ++dl) {                                     \
            const int s_ = ((U) + dl) % 11;                                   \
            const float wd = wk.w[dl];                                        \
            ax[s_]  += wd * hx;  ay[s_]  += wd * hy;                          \
            ass[s_] += wd * hss; axy[s_] += wd * hxy;                         \
        }                                                                     \
        {   /* restart the slot emitted last step (dead or zero) */          \
            const int s_ = ((U) + 10) % 11;                                   \
            const float wd = wk.w[10];                                        \
            ax[s_]  = wd * hx;  ay[s_]  = wd * hy;                            \
            ass[s_] = wd * hss; axy[s_] = wd * hxy;                           \
        }                                                                     \
        {                                                                     \
            const float mx  = ax[(U)], my = ay[(U)];                          \
            const float mx2 = mx * mx, my2 = my * my, mxy = mx * my;          \
            const float sgs = ass[(U)] - mx2 - my2;                           \
            const float sgx = axy[(U)] - mxy;                                 \
            const float num = (2.f * mxy + 1e-4f) * (2.f * sgx + 9e-4f);      \
            const float den = (mx2 + my2 + 1e-4f) * (sgs + 9e-4f) + 1e-12f;   \
            lsum += (AW) * (num * __builtin_amdgcn_rcpf(den));                \
        }                                                                     \
    }

    // groups 0..5: 11 steps each. even U: load->A, write B->c1, read c0;
    // odd U: load->B, write A->c0, read c1. A<->B swapped per group (11 odd).
    int pg = 0;
    #pragma unroll 1
    for (int g = 0; g < 6; ++g) {
        const int brow = R0 - 3 + 11 * g;
        const float amg = (g == 0) ? 0.f : 1.f;   // g0: only U=10 emits
        float* __restrict__ cx0 = rbuf[w][pg][0];
        float* __restrict__ cy0 = rbuf[w][pg][1];
        float* __restrict__ cx1 = rbuf[w][pg ^ 1][0];
        float* __restrict__ cy1 = rbuf[w][pg ^ 1][1];
        SSTEP(0, 1,1, amg, Ax,Ay,Axt,Ayt, Bx,By,Bxt,Byt, cx0,cy0, cx1,cy1)
        SSTEP(1, 1,1, amg, Bx,By,Bxt,Byt, Ax,Ay,Axt,Ayt, cx1,cy1, cx0,cy0)
        SSTEP(2, 1,1, amg, Ax,Ay,Axt,Ayt, Bx,By,Bxt,Byt, cx0,cy0, cx1,cy1)
        SSTEP(3, 1,1, amg, Bx,By,Bxt,Byt, Ax,Ay,Axt,Ayt, cx1,cy1, cx0,cy0)
        SSTEP(4, 1,1, amg, Ax,Ay,Axt,Ayt, Bx,By,Bxt,Byt, cx0,cy0, cx1,cy1)
        SSTEP(5, 1,1, amg, Bx,By,Bxt,Byt, Ax,Ay,Axt,Ayt, cx1,cy1, cx0,cy0)
        SSTEP(6, 1,1, amg, Ax,Ay,Axt,Ayt, Bx,By,Bxt,Byt, cx0,cy0, cx1,cy1)
        SSTEP(7, 1,1, amg, Bx,By,Bxt,Byt, Ax,Ay,Axt,Ayt, cx1,cy1, cx0,cy0)
        SSTEP(8, 1,1, amg, Ax,Ay,Axt,Ayt, Bx,By,Bxt,Byt, cx0,cy0, cx1,cy1)
        SSTEP(9, 1,1, amg, Bx,By,Bxt,Byt, Ax,Ay,Axt,Ayt, cx1,cy1, cx0,cy0)
        SSTEP(10,1,1, 1.0f, Ax,Ay,Axt,Ayt, Bx,By,Bxt,Byt, cx0,cy0, cx1,cy1)
        { float t;
          t=Ax; Ax=Bx; Bx=t;   t=Ay; Ay=By; By=t;
          t=Axt;Axt=Bxt;Bxt=t; t=Ayt;Ayt=Byt;Byt=t; }
        pg ^= 1;
    }

    // tail group: i = 66..73 (U=0..7); pg==0 here. loads end at i=71,
    // writes at i=72 (last consumed row R0+68 read at i=73).
    {
        const int brow = R0 - 3 + 66;
        float* __restrict__ cx0 = rbuf[w][0][0];
        float* __restrict__ cy0 = rbuf[w][0][1];
        float* __restrict__ cx1 = rbuf[w][1][0];
        float* __restrict__ cy1 = rbuf[w][1][1];
        SSTEP(0, 1,1, 1.0f, Ax,Ay,Axt,Ayt, Bx,By,Bxt,Byt, cx0,cy0, cx1,cy1)
        SSTEP(1, 1,1, 1.0f, Bx,By,Bxt,Byt, Ax,Ay,Axt,Ayt, cx1,cy1, cx0,cy0)
        SSTEP(2, 1,1, 1.0f, Ax,Ay,Axt,Ayt, Bx,By,Bxt,Byt, cx0,cy0, cx1,cy1)
        SSTEP(3, 1,1, 1.0f, Bx,By,Bxt,Byt, Ax,Ay,Axt,Ayt, cx1,cy1, cx0,cy0)
        SSTEP(4, 1,1, 1.0f, Ax,Ay,Axt,Ayt, Bx,By,Bxt,Byt, cx0,cy0, cx1,cy1)
        SSTEP(5, 1,1, 1.0f, Bx,By,Bxt,Byt, Ax,Ay,Axt,Ayt, cx1,cy1, cx0,cy0)
        SSTEP(6, 0,1, 1.0f, Ax,Ay,Axt,Ayt, Bx,By,Bxt,Byt, cx0,cy0, cx1,cy1)
        SSTEP(7, 0,0, 1.0f, Bx,By,Bxt,Byt, Ax,Ay,Axt,Ayt, cx1,cy1, cx0,cy0)
    }
#undef SSTEP

    // ---- wave reduction (waves fully independent) ----
    #pragma unroll
    for (int off = 32; off; off >>= 1) lsum += __shfl_down(lsum, off);
    if (l == 0) {
        if (atomic_mode) atomicAdd(partial, lsum);
        else partial[wid] = lsum;
    }
}

__global__ __launch_bounds__(1024) void ssim_fin(const float* __restrict__ partial,
                                                 float* __restrict__ out, int n)
{
    float s = 0.f;
    for (int i = threadIdx.x; i < n; i += 1024) s += partial[i];
    #pragma unroll
    for (int off = 32; off; off >>= 1) s += __shfl_down(s, off);
    __shared__ float red[16];
    if ((threadIdx.x & 63) == 0) red[threadIdx.x >> 6] = s;
    __syncthreads();
    if (threadIdx.x == 0) {
        float v = 0.f;
        #pragma unroll
        for (int i = 0; i < 16; ++i) v += red[i];
        out[0] = 1.0f - v * (1.0f / 16777216.0f);
    }
}

extern "C" void kernel_launch(void* const* d_in, const int* in_sizes, int n_in,
                              void* d_out, int out_size, void* d_ws, size_t ws_size,
                              hipStream_t stream) {
    const float* x = (const float*)d_in[0];
    const float* y = (const float*)d_in[1];
    float* out = (float*)d_out;
    float* ws  = (float*)d_ws;

    W11 wk;
    double e[11], s = 0.0;
    for (int i = 0; i < 11; ++i) {
        double d = (double)i - 5.0;
        e[i] = exp(-(d * d) / 4.5);
        s += e[i];
    }
    for (int i = 0; i < 11; ++i) wk.w[i] = (float)(e[i] / s);

    const bool use_partial = ws_size >= (size_t)NPART * sizeof(float);
    if (!use_partial) hipMemsetAsync(d_ws, 0, sizeof(float), stream);

    hipLaunchKernelGGL(ssim_main, dim3(1024), dim3(256), 0, stream,
                       x, y, ws, wk, use_partial ? 0 : 1);
    hipLaunchKernelGGL(ssim_fin, dim3(1), dim3(1024), 0, stream,
                       ws, out, use_partial ? NPART : 1);
}

// Round 10
// 209.574 us; speedup vs baseline: 3.1138x; 3.1138x over previous
//
#include <hip/hip_runtime.h>
#include <math.h>

// SSIM loss fp32, B=64 H=W=512, 11x11 Gaussian sigma=1.5, separable (w ⊗ w).
// R18 = R13 (130us, proven, VGPR 52, no spill) + occupancy lever.
// R14/R17 streaming post-mortem: 44-float v-conv ring spilled to scratch both
// times (WRITE_SIZE 58MB/1.07GB, VGPR stuck 64) -> design abandoned.
// R13 residual: VALUBusy 41%, Occupancy 42% (LDS 37.9KB -> 4 blocks/CU).
// R18 changes (dataflow untouched):
//  - LDS union: raw (16.1KB) dies after stage-2 reads; hst (21.5KB) born
//    after. One 21.5KB buffer; stage-2 = compute->regs / barrier / write.
//    LDS 37.9 -> 21.5KB => 7 blocks/CU (28 waves, 87.5% cap vs 50%).
//  - __launch_bounds__(256,7): budget 73 regs >= 52 needed.
//  - XCD-chunked block swizzle (bijective bit-rotate): each XCD works 8
//    complete images -> halo re-reads hit its private L2.

typedef float v2f __attribute__((ext_vector_type(2)));

#define TSY  32                  // output rows per block
#define HR   42                  // h-rows = TSY + 10
#define RAWS 48                  // raw row stride floats
#define GX   16
#define GY   16
#define NPART (64 * GY * GX)     // 16384

struct W11 { float w[11]; };

__global__ __launch_bounds__(256, 7) void ssim_main(
    const float* __restrict__ x, const float* __restrict__ y,
    float* __restrict__ partial, W11 wk, int atomic_mode)
{
    // union region: phase A = raw[2][42][48] floats (4032 f);
    //               phase B = hst v2f[4*16*42] (5376 f). 21504 B total.
    __shared__ __align__(16) float lds[5376];
    __shared__ float red[4];

    const int tid = threadIdx.x;
    // XCD-chunked swizzle: lin 14b, rotate low 3 bits to top -> each XCD
    // (round-robin on dispatch index) gets a contiguous 2048-block chunk
    // = 8 complete images.
    const int lin = (int)blockIdx.x + 16 * ((int)blockIdx.y + 16 * (int)blockIdx.z);
    const int swz = ((lin & 7) << 11) | (lin >> 3);
    const int bx = swz & 15, by = (swz >> 4) & 15, bz = swz >> 8;
    const float* __restrict__ xb = x + (size_t)bz * (512 * 512);
    const float* __restrict__ yb = y + (size_t)bz * (512 * 512);
    const int ox = bx * 32;
    const int oy = by * TSY;

    // ---- stage 1: coalesced global -> LDS raw staging (zero-padded) ----
    // 1008 f4 tasks, dst flat-contiguous -> conflict-free writes.
    #pragma unroll
    for (int it = 0; it < 4; ++it) {
        const int i = tid + (it << 8);
        if (i < 1008) {
            const int a   = (i >= 504) ? 1 : 0;
            const int j   = i - a * 504;
            const int row = j / 12;          // 0..41
            const int f4c = j - row * 12;    // 0..11
            const int gr  = oy - 5 + row;
            const int gc  = ox - 8 + (f4c << 2);
            const float* __restrict__ sb = a ? yb : xb;
            float4 v = {0.f, 0.f, 0.f, 0.f};
            if ((unsigned)gr < 512u) {
                const float* __restrict__ rp = sb + gr * 512;
                if ((unsigned)gc <= 508u) {  // uniform-true for bx 1..14
                    v = *(const float4*)(rp + gc);
                } else {
                    float e[4];
                    #pragma unroll
                    for (int t = 0; t < 4; ++t) {
                        const int c = gc + t;
                        e[t] = ((unsigned)c < 512u) ? rp[c] : 0.f;
                    }
                    v = make_float4(e[0], e[1], e[2], e[3]);
                }
            }
            ((float4*)lds)[i] = v;
        }
    }
    __syncthreads();

    // ---- stage 2a: horizontal convs -> registers (168 active threads) ----
    const bool active = (tid < HR * 4);
    const int r = tid >> 2;
    const int g = tid & 3;
    v2f acc[4][4];
    if (active) {
        const float4* __restrict__ px = (const float4*)(lds + r * RAWS + (g << 2));
        const float4* __restrict__ py = (const float4*)(lds + 2016 + r * RAWS + (g << 2));
        float4 X[9], Y[9];
        #pragma unroll
        for (int k = 0; k < 9; ++k) X[k] = px[k];
        #pragma unroll
        for (int k = 0; k < 9; ++k) Y[k] = py[k];
        float fx[36], fy[36];
        #pragma unroll
        for (int k = 0; k < 9; ++k) {
            fx[4*k+0] = X[k].x; fx[4*k+1] = X[k].y;
            fx[4*k+2] = X[k].z; fx[4*k+3] = X[k].w;
            fy[4*k+0] = Y[k].x; fy[4*k+1] = Y[k].y;
            fy[4*k+2] = Y[k].z; fy[4*k+3] = Y[k].w;
        }
        #pragma unroll
        for (int q = 0; q < 4; ++q)
            #pragma unroll
            for (int oc = 0; oc < 4; ++oc) acc[q][oc] = (v2f)0.f;
        #pragma unroll
        for (int k = 0; k < 14; ++k) {
            const v2f xv = (v2f){fx[3 + k], fx[19 + k]};
            const v2f yv = (v2f){fy[3 + k], fy[19 + k]};
            const v2f ss = xv * xv + yv * yv;
            const v2f xy = xv * yv;
            #pragma unroll
            for (int oc = 0; oc < 4; ++oc) {
                const int j = k - oc;            // compile-time
                if (j < 0 || j > 10) continue;
                const float wj = wk.w[j];
                acc[0][oc] += wj * xv;
                acc[1][oc] += wj * yv;
                acc[2][oc] += wj * ss;
                acc[3][oc] += wj * xy;
            }
        }
    }
    __syncthreads();   // all raw reads done -> safe to overwrite with hst

    // ---- stage 2b: write h-conv results over the raw region ----
    // hst v2f layout: [q*672 + c*42 + r], c = 4g+oc (lanes = cols c, c+16).
    if (active) {
        v2f* __restrict__ hst = (v2f*)lds;
        #pragma unroll
        for (int q = 0; q < 4; ++q)
            #pragma unroll
            for (int oc = 0; oc < 4; ++oc)
                hst[q * 672 + ((g << 2) + oc) * HR + r] = acc[q][oc];
    }
    __syncthreads();

    // ---- stage 3: vertical convs + SSIM; 256 tasks = 16 cp x 16 row-pairs
    // b128 starts (84*cp + 4*rp) mod 32 cycle all 32 banks: conflict-free.
    const int cp = tid & 15;
    const int m0 = (tid >> 4) << 1;              // output rows m0, m0+1
    float lsum = 0.f;
    {
        const v2f* __restrict__ hst = (const v2f*)lds;
        v2f s[4][2];
        #pragma unroll
        for (int q = 0; q < 4; ++q) {
            const float4* __restrict__ p4 = (const float4*)(hst + q * 672 + cp * HR + m0);
            float4 Q[6];
            #pragma unroll
            for (int k = 0; k < 6; ++k) Q[k] = p4[k];   // h-rows m0..m0+11
            #pragma unroll
            for (int o = 0; o < 2; ++o) {
                v2f a = (v2f)0.f;
                #pragma unroll
                for (int j = 0; j < 11; ++j) {
                    const int t = o + j;                 // 0..11 compile-time
                    const v2f rv = (t & 1) ? (v2f){Q[t >> 1].z, Q[t >> 1].w}
                                           : (v2f){Q[t >> 1].x, Q[t >> 1].y};
                    a += wk.w[j] * rv;
                }
                s[q][o] = a;
            }
        }

        const float C1 = 1e-4f, C2 = 9e-4f;
        #pragma unroll
        for (int o = 0; o < 2; ++o) {
            const v2f mx = s[0][o], my = s[1][o];
            const v2f mx2 = mx * mx, my2 = my * my, mxy = mx * my;
            const v2f sig_sum = s[2][o] - mx2 - my2;   // sigma_x2 + sigma_y2
            const v2f sig_xy  = s[3][o] - mxy;
            const v2f num = (2.f * mxy + C1) * (2.f * sig_xy + C2);
            const v2f den = (mx2 + my2 + C1) * (sig_sum + C2) + 1e-12f;
            lsum += num.x * __builtin_amdgcn_rcpf(den.x)
                  + num.y * __builtin_amdgcn_rcpf(den.y);
        }
    }

    // ---- block reduction (4 waves) ----
    #pragma unroll
    for (int off = 32; off; off >>= 1) lsum += __shfl_down(lsum, off);
    if ((tid & 63) == 0) red[tid >> 6] = lsum;
    __syncthreads();
    if (tid == 0) {
        const float v = red[0] + red[1] + red[2] + red[3];
        if (atomic_mode) atomicAdd(partial, v);
        else partial[(bz * GY + by) * GX + bx] = v;
    }
}

__global__ __launch_bounds__(1024) void ssim_fin(const float* __restrict__ partial,
                                                 float* __restrict__ out, int n)
{
    float s = 0.f;
    for (int i = threadIdx.x; i < n; i += 1024) s += partial[i];
    #pragma unroll
    for (int off = 32; off; off >>= 1) s += __shfl_down(s, off);
    __shared__ float red[16];
    if ((threadIdx.x & 63) == 0) red[threadIdx.x >> 6] = s;
    __syncthreads();
    if (threadIdx.x == 0) {
        float v = 0.f;
        #pragma unroll
        for (int i = 0; i < 16; ++i) v += red[i];
        out[0] = 1.0f - v * (1.0f / 16777216.0f);
    }
}

extern "C" void kernel_launch(void* const* d_in, const int* in_sizes, int n_in,
                              void* d_out, int out_size, void* d_ws, size_t ws_size,
                              hipStream_t stream) {
    const float* x = (const float*)d_in[0];
    const float* y = (const float*)d_in[1];
    float* out = (float*)d_out;
    float* ws  = (float*)d_ws;

    W11 wk;
    double e[11], s = 0.0;
    for (int i = 0; i < 11; ++i) {
        double d = (double)i - 5.0;
        e[i] = exp(-(d * d) / 4.5);
        s += e[i];
    }
    for (int i = 0; i < 11; ++i) wk.w[i] = (float)(e[i] / s);

    const bool use_partial = ws_size >= (size_t)NPART * sizeof(float);
    if (!use_partial) hipMemsetAsync(d_ws, 0, sizeof(float), stream);

    hipLaunchKernelGGL(ssim_main, dim3(GX, GY, 64), dim3(256), 0, stream,
                       x, y, ws, wk, use_partial ? 0 : 1);
    hipLaunchKernelGGL(ssim_fin, dim3(1), dim3(1024), 0, stream,
                       ws, out, use_partial ? NPART : 1);
}